// Round 4
// baseline (133.447 us; speedup 1.0000x reference)
//
#include <hip/hip_runtime.h>
#include <cstdint>
#include <cstddef>

// 2-layer GCN. norm factorization: out[d] = dinv[d]*(h_s[d] + sum_{s->d} h_s[s]),
// h_s[i] = dinv[i]*(x@W)[i]. Self-loop folded in as the h_s[d] term.
// Edge aggregation: deterministic-layout 2-level counting sort -> CSR -> per-node
// float4 gather (no global atomics on the feature path).

#define SHIFT 7                 // 128 nodes per coarse bucket
#define NPB 128
#define CHUNK 8192              // edges per histogram/scatter block
#define IMG_CAP 8192            // LDS csr-image capacity (~4x expected bucket load)

__device__ __forceinline__ void f4acc(float4& a, const float4& b) {
  a.x += b.x; a.y += b.y; a.z += b.z; a.w += b.w;
}

// ---- K1: per-block bucket histogram. hist[b*nWG + w] = count of bucket b in block w ----
__global__ __launch_bounds__(256) void hist_kernel(const int* __restrict__ dst, int E, int nWG,
                                                   int B, int* __restrict__ hist) {
  __shared__ int h[512];
  int t = threadIdx.x, w = blockIdx.x;
  for (int i = t; i < B; i += 256) h[i] = 0;
  __syncthreads();
  int beg = w * CHUNK, end = min(beg + CHUNK, E);
  for (int i = beg + t; i < end; i += 256) atomicAdd(&h[dst[i] >> SHIFT], 1);
  __syncthreads();
  for (int i = t; i < B; i += 256) hist[i * nWG + w] = h[i];
}

// ---- K2a: exclusive scan of each bucket row (over blocks); also row total ----
__global__ __launch_bounds__(256) void rowscan_kernel(const int* __restrict__ hist, int nWG,
                                                      int* __restrict__ rowscan, int* __restrict__ total) {
  int b = blockIdx.x, t = threadIdx.x;  // nWG <= 256
  int v = (t < nWG) ? hist[b * nWG + t] : 0;
  int lane = t & 63, wid = t >> 6;
  int x = v;
#pragma unroll
  for (int o = 1; o < 64; o <<= 1) { int y = __shfl_up(x, o, 64); if (lane >= o) x += y; }
  __shared__ int wsum[4];
  if (lane == 63) wsum[wid] = x;
  __syncthreads();
  int bw = 0;
  for (int i = 0; i < wid; ++i) bw += wsum[i];
  int incl = bw + x;
  if (t < nWG) rowscan[b * nWG + t] = incl - v;
  if (t == nWG - 1) total[b] = incl;
}

// ---- K2b: exclusive scan of bucket totals -> base[b]; base[B] = E ----
__global__ __launch_bounds__(512) void basescan_kernel(const int* __restrict__ total, int B,
                                                       int* __restrict__ base) {
  int t = threadIdx.x;  // B < 512
  int v = (t < B) ? total[t] : 0;
  int lane = t & 63, wid = t >> 6;
  int x = v;
#pragma unroll
  for (int o = 1; o < 64; o <<= 1) { int y = __shfl_up(x, o, 64); if (lane >= o) x += y; }
  __shared__ int wsum[8];
  if (lane == 63) wsum[wid] = x;
  __syncthreads();
  int bw = 0;
  for (int i = 0; i < wid; ++i) bw += wsum[i];
  int excl = bw + x - v;
  if (t <= B) base[t] = excl;
}

// ---- K3: scatter packed keys (local<<16 | src) into bucket-contiguous layout ----
__global__ __launch_bounds__(256) void scatterkeys_kernel(const int* __restrict__ src,
                                                          const int* __restrict__ dst, int E, int nWG,
                                                          int B, const int* __restrict__ rowscan,
                                                          const int* __restrict__ base,
                                                          unsigned* __restrict__ keys) {
  __shared__ int cur[512];
  int t = threadIdx.x, w = blockIdx.x;
  for (int i = t; i < B; i += 256) cur[i] = base[i] + rowscan[i * nWG + w];
  __syncthreads();
  int beg = w * CHUNK, end = min(beg + CHUNK, E);
  for (int i = beg + t; i < end; i += 256) {
    int d = dst[i], s = src[i];
    int b = d >> SHIFT;
    int p = atomicAdd(&cur[b], 1);
    keys[p] = ((unsigned)(d & (NPB - 1)) << 16) | (unsigned)s;  // requires N <= 65536
  }
}

// ---- K4: per-bucket: per-node counts -> eoff/ecnt/dinv; sort keys -> csr (LDS image) ----
__global__ __launch_bounds__(256) void bucket_build_kernel(const unsigned* __restrict__ keys,
                                                           const int* __restrict__ base, int N,
                                                           int* __restrict__ csr, int* __restrict__ eoff,
                                                           int* __restrict__ ecnt, float* __restrict__ dinv) {
  __shared__ int cnt[NPB], loffs[NPB], cur[NPB];
  __shared__ int image[IMG_CAP];
  int b = blockIdx.x, t = threadIdx.x;
  int nb = b << SHIFT;
  int nn = min(NPB, N - nb);
  int gbeg = base[b], gend = base[b + 1];
  int m = gend - gbeg;
  if (t < NPB) cnt[t] = 0;
  __syncthreads();
  for (int i = gbeg + t; i < gend; i += 256) atomicAdd(&cnt[keys[i] >> 16], 1);
  __syncthreads();
  if (t < 64) {  // pair-wise exclusive scan of cnt[0..127] in one wave
    int v0 = cnt[2 * t], v1 = cnt[2 * t + 1];
    int s = v0 + v1, x = s;
#pragma unroll
    for (int o = 1; o < 64; o <<= 1) { int y = __shfl_up(x, o, 64); if (t >= o) x += y; }
    int e = x - s;
    loffs[2 * t] = e;      cur[2 * t] = e;
    loffs[2 * t + 1] = e + v0;  cur[2 * t + 1] = e + v0;
  }
  __syncthreads();
  for (int n = t; n < nn; n += 256) {
    eoff[nb + n] = gbeg + loffs[n];
    ecnt[nb + n] = cnt[n];
    dinv[nb + n] = 1.0f / sqrtf((float)(cnt[n] + 1));  // +1 self-loop
  }
  if (m <= IMG_CAP) {
    for (int i = gbeg + t; i < gend; i += 256) {
      unsigned k = keys[i];
      int p = atomicAdd(&cur[k >> 16], 1);
      image[p] = (int)(k & 0xFFFFu);
    }
    __syncthreads();
    for (int i = t; i < m; i += 256) csr[gbeg + i] = image[i];
  } else {  // statistically unreachable fallback
    for (int i = gbeg + t; i < gend; i += 256) {
      unsigned k = keys[i];
      int p = atomicAdd(&cur[k >> 16], 1);
      csr[gbeg + p] = (int)(k & 0xFFFFu);
    }
  }
}

// ---- GEMM1: h1s[i][c] = dinv[i] * (x @ W1)[i][c]   (N x 128 @ 128 x 64) ----
__global__ __launch_bounds__(256) void gemm1_kernel(
    const float* __restrict__ x, const float* __restrict__ W1,
    const float* __restrict__ dinv, float* __restrict__ h1s, int N) {
  __shared__ float ws[128 * 64];
  __shared__ float xs[64 * 128];
  const int t = threadIdx.x;
  const int rowBase = blockIdx.x * 64;
  float4* ws4 = (float4*)ws;
  float4* xs4 = (float4*)xs;
  for (int i = t; i < 128 * 16; i += 256) ws4[i] = ((const float4*)W1)[i];
  for (int i = t; i < 64 * 32; i += 256) {
    int r = i >> 5, kq = i & 31;
    int row = rowBase + r;
    float4 v = make_float4(0.f, 0.f, 0.f, 0.f);
    if (row < N) v = ((const float4*)x)[(size_t)row * 32 + kq];
    xs4[r * 32 + (kq ^ ((r >> 2) & 7))] = v;
  }
  __syncthreads();
  const int g = t & 15;
  const int rg = t >> 4;
  const int swz = rg & 7;
  float acc[4][4] = {};
  for (int kq = 0; kq < 32; ++kq) {
    float4 a[4];
#pragma unroll
    for (int j = 0; j < 4; ++j) a[j] = xs4[(4 * rg + j) * 32 + (kq ^ swz)];
    float4 w[4];
#pragma unroll
    for (int kk = 0; kk < 4; ++kk) w[kk] = ws4[(4 * kq + kk) * 16 + g];
#pragma unroll
    for (int j = 0; j < 4; ++j) {
      acc[j][0] += a[j].x * w[0].x + a[j].y * w[1].x + a[j].z * w[2].x + a[j].w * w[3].x;
      acc[j][1] += a[j].x * w[0].y + a[j].y * w[1].y + a[j].z * w[2].y + a[j].w * w[3].y;
      acc[j][2] += a[j].x * w[0].z + a[j].y * w[1].z + a[j].z * w[2].z + a[j].w * w[3].z;
      acc[j][3] += a[j].x * w[0].w + a[j].y * w[1].w + a[j].z * w[2].w + a[j].w * w[3].w;
    }
  }
#pragma unroll
  for (int j = 0; j < 4; ++j) {
    int row = rowBase + 4 * rg + j;
    if (row < N) {
      float dv = dinv[row];
      float4 o = make_float4(acc[j][0] * dv, acc[j][1] * dv, acc[j][2] * dv, acc[j][3] * dv);
      ((float4*)h1s)[(size_t)row * 16 + g] = o;
    }
  }
}

// ---- gather layer 1: 1 wave/node, 16-lane x float4 subgroups -> 4 edges per vmem instr ----
__global__ __launch_bounds__(256) void gather64_kernel(
    const float* __restrict__ h1s, const int* __restrict__ csr, const int* __restrict__ eoff,
    const int* __restrict__ ecnt, const float* __restrict__ dinv, const float* __restrict__ b1,
    float* __restrict__ a1, int N) {
  int t = threadIdx.x;
  int d = blockIdx.x * 4 + (t >> 6);
  if (d >= N) return;
  int lane = t & 63;
  int sub = lane >> 4;  // 0..3: edge slot within group of 4
  int q = lane & 15;    // float4 column
  int beg = eoff[d], m = ecnt[d];
  const float4* h4 = (const float4*)h1s;  // row stride 16 float4
  float4 acc = make_float4(0.f, 0.f, 0.f, 0.f);
  float4 acc2 = make_float4(0.f, 0.f, 0.f, 0.f);
  if (sub == 0) acc = h4[(size_t)d * 16 + q];  // self-loop
  int j = 0;
  for (; j + 8 <= m; j += 8) {  // 8 rows (8 KB) in flight
    int s0 = csr[beg + j + sub];
    int s1 = csr[beg + j + 4 + sub];
    float4 v0 = h4[(size_t)s0 * 16 + q];
    float4 v1 = h4[(size_t)s1 * 16 + q];
    f4acc(acc, v0);
    f4acc(acc2, v1);
  }
  for (; j + 4 <= m; j += 4) {
    int s0 = csr[beg + j + sub];
    float4 v0 = h4[(size_t)s0 * 16 + q];
    f4acc(acc, v0);
  }
  if (j + sub < m) {
    int s0 = csr[beg + j + sub];
    float4 v0 = h4[(size_t)s0 * 16 + q];
    f4acc(acc2, v0);
  }
  f4acc(acc, acc2);
  acc.x += __shfl_xor(acc.x, 16, 64); acc.x += __shfl_xor(acc.x, 32, 64);
  acc.y += __shfl_xor(acc.y, 16, 64); acc.y += __shfl_xor(acc.y, 32, 64);
  acc.z += __shfl_xor(acc.z, 16, 64); acc.z += __shfl_xor(acc.z, 32, 64);
  acc.w += __shfl_xor(acc.w, 16, 64); acc.w += __shfl_xor(acc.w, 32, 64);
  if (sub == 0) {
    float dv = dinv[d];
    float4 bb = ((const float4*)b1)[q];
    float4 o;
    o.x = fmaxf(acc.x * dv + bb.x, 0.f);
    o.y = fmaxf(acc.y * dv + bb.y, 0.f);
    o.z = fmaxf(acc.z * dv + bb.z, 0.f);
    o.w = fmaxf(acc.w * dv + bb.w, 0.f);
    ((float4*)a1)[(size_t)d * 16 + q] = o;
  }
}

// ---- GEMM2: h2s[i][c] = dinv[i] * (a1 @ W2)[i][c]   (N x 64 @ 64 x 32) ----
__global__ __launch_bounds__(256) void gemm2_kernel(
    const float* __restrict__ a1, const float* __restrict__ W2,
    const float* __restrict__ dinv, float* __restrict__ h2s, int N) {
  __shared__ float ws[64 * 32];
  __shared__ float xs[128 * 64];
  const int t = threadIdx.x;
  const int rowBase = blockIdx.x * 128;
  float4* ws4 = (float4*)ws;
  float4* xs4 = (float4*)xs;
  for (int i = t; i < 64 * 8; i += 256) ws4[i] = ((const float4*)W2)[i];
  for (int i = t; i < 128 * 16; i += 256) {
    int r = i >> 4, kq = i & 15;
    int row = rowBase + r;
    float4 v = make_float4(0.f, 0.f, 0.f, 0.f);
    if (row < N) v = ((const float4*)a1)[(size_t)row * 16 + kq];
    xs4[r * 16 + (kq ^ ((r >> 2) & 7))] = v;
  }
  __syncthreads();
  const int g = t & 7;
  const int rg = t >> 3;
  const int swz = rg & 7;
  float acc[4][4] = {};
  for (int kq = 0; kq < 16; ++kq) {
    float4 a[4];
#pragma unroll
    for (int j = 0; j < 4; ++j) a[j] = xs4[(4 * rg + j) * 16 + (kq ^ swz)];
    float4 w[4];
#pragma unroll
    for (int kk = 0; kk < 4; ++kk) w[kk] = ws4[(4 * kq + kk) * 8 + g];
#pragma unroll
    for (int j = 0; j < 4; ++j) {
      acc[j][0] += a[j].x * w[0].x + a[j].y * w[1].x + a[j].z * w[2].x + a[j].w * w[3].x;
      acc[j][1] += a[j].x * w[0].y + a[j].y * w[1].y + a[j].z * w[2].y + a[j].w * w[3].y;
      acc[j][2] += a[j].x * w[0].z + a[j].y * w[1].z + a[j].z * w[2].z + a[j].w * w[3].z;
      acc[j][3] += a[j].x * w[0].w + a[j].y * w[1].w + a[j].z * w[2].w + a[j].w * w[3].w;
    }
  }
#pragma unroll
  for (int j = 0; j < 4; ++j) {
    int row = rowBase + 4 * rg + j;
    if (row < N) {
      float dv = dinv[row];
      float4 o = make_float4(acc[j][0] * dv, acc[j][1] * dv, acc[j][2] * dv, acc[j][3] * dv);
      ((float4*)h2s)[(size_t)row * 8 + g] = o;
    }
  }
}

// ---- gather layer 2: 1 wave/node, 8-lane x float4 subgroups -> 8 edges per vmem instr ----
__global__ __launch_bounds__(256) void gather32_kernel(
    const float* __restrict__ h2s, const int* __restrict__ csr, const int* __restrict__ eoff,
    const int* __restrict__ ecnt, const float* __restrict__ dinv, const float* __restrict__ b2,
    float* __restrict__ out, int N) {
  int t = threadIdx.x;
  int d = blockIdx.x * 4 + (t >> 6);
  if (d >= N) return;
  int lane = t & 63;
  int sub = lane >> 3;  // 0..7
  int q = lane & 7;     // float4 column
  int beg = eoff[d], m = ecnt[d];
  const float4* h4 = (const float4*)h2s;  // row stride 8 float4
  float4 acc = make_float4(0.f, 0.f, 0.f, 0.f);
  float4 acc2 = make_float4(0.f, 0.f, 0.f, 0.f);
  if (sub == 0) acc = h4[(size_t)d * 8 + q];  // self-loop
  int j = 0;
  for (; j + 16 <= m; j += 16) {
    int s0 = csr[beg + j + sub];
    int s1 = csr[beg + j + 8 + sub];
    float4 v0 = h4[(size_t)s0 * 8 + q];
    float4 v1 = h4[(size_t)s1 * 8 + q];
    f4acc(acc, v0);
    f4acc(acc2, v1);
  }
  for (; j + 8 <= m; j += 8) {
    int s0 = csr[beg + j + sub];
    float4 v0 = h4[(size_t)s0 * 8 + q];
    f4acc(acc, v0);
  }
  if (j + sub < m) {
    int s0 = csr[beg + j + sub];
    float4 v0 = h4[(size_t)s0 * 8 + q];
    f4acc(acc2, v0);
  }
  f4acc(acc, acc2);
  acc.x += __shfl_xor(acc.x, 8, 64); acc.x += __shfl_xor(acc.x, 16, 64); acc.x += __shfl_xor(acc.x, 32, 64);
  acc.y += __shfl_xor(acc.y, 8, 64); acc.y += __shfl_xor(acc.y, 16, 64); acc.y += __shfl_xor(acc.y, 32, 64);
  acc.z += __shfl_xor(acc.z, 8, 64); acc.z += __shfl_xor(acc.z, 16, 64); acc.z += __shfl_xor(acc.z, 32, 64);
  acc.w += __shfl_xor(acc.w, 8, 64); acc.w += __shfl_xor(acc.w, 16, 64); acc.w += __shfl_xor(acc.w, 32, 64);
  if (sub == 0) {
    float dv = dinv[d];
    float4 bb = ((const float4*)b2)[q];
    float4 o;
    o.x = acc.x * dv + bb.x;
    o.y = acc.y * dv + bb.y;
    o.z = acc.z * dv + bb.z;
    o.w = acc.w * dv + bb.w;
    ((float4*)out)[(size_t)d * 8 + q] = o;
  }
}

extern "C" void kernel_launch(void* const* d_in, const int* in_sizes, int n_in,
                              void* d_out, int out_size, void* d_ws, size_t ws_size,
                              hipStream_t stream) {
  const float* x = (const float*)d_in[0];
  const int* edge_index = (const int*)d_in[1];
  // d_in[2] = edge_attr (unused by reference)
  const float* W1 = (const float*)d_in[3];
  const float* b1 = (const float*)d_in[4];
  const float* W2 = (const float*)d_in[5];
  const float* b2 = (const float*)d_in[6];
  float* out = (float*)d_out;

  const int N = in_sizes[0] / 128;  // 50000 (key packing requires <= 65536)
  const int E = in_sizes[1] / 2;    // 800000
  const int* src = edge_index;
  const int* dst = edge_index + E;

  const int B = (N + NPB - 1) >> SHIFT;     // 391 buckets
  const int nWG = (E + CHUNK - 1) / CHUNK;  // 98 blocks

  char* ws = (char*)d_ws;
  size_t off = 0;
  auto alloc = [&](size_t bytes) -> void* {
    void* p = ws + off;
    off += (bytes + 255) & ~(size_t)255;
    return p;
  };
  unsigned* keys = (unsigned*)alloc((size_t)E * 4);
  int* csr = (int*)alloc((size_t)E * 4);
  int* hist = (int*)alloc((size_t)B * nWG * 4);
  int* rowscan = (int*)alloc((size_t)B * nWG * 4);
  int* total = (int*)alloc((size_t)B * 4);
  int* base = (int*)alloc((size_t)(B + 1) * 4);
  int* eoff = (int*)alloc((size_t)N * 4);
  int* ecnt = (int*)alloc((size_t)N * 4);
  float* dinv = (float*)alloc((size_t)N * 4);
  float* h1s = (float*)alloc((size_t)N * 64 * 4);
  float* a1 = (float*)alloc((size_t)N * 64 * 4);
  float* h2s = h1s;  // alias: h1s dead after gather64

  hist_kernel<<<nWG, 256, 0, stream>>>(dst, E, nWG, B, hist);
  rowscan_kernel<<<B, 256, 0, stream>>>(hist, nWG, rowscan, total);
  basescan_kernel<<<1, 512, 0, stream>>>(total, B, base);
  scatterkeys_kernel<<<nWG, 256, 0, stream>>>(src, dst, E, nWG, B, rowscan, base, keys);
  bucket_build_kernel<<<B, 256, 0, stream>>>(keys, base, N, csr, eoff, ecnt, dinv);
  gemm1_kernel<<<(N + 63) / 64, 256, 0, stream>>>(x, W1, dinv, h1s, N);
  gather64_kernel<<<(N + 3) / 4, 256, 0, stream>>>(h1s, csr, eoff, ecnt, dinv, b1, a1, N);
  gemm2_kernel<<<(N + 127) / 128, 256, 0, stream>>>(a1, W2, dinv, h2s, N);
  gather32_kernel<<<(N + 3) / 4, 256, 0, stream>>>(h2s, csr, eoff, ecnt, dinv, b2, out, N);
}

// Round 5
// 121.472 us; speedup vs baseline: 1.0986x; 1.0986x over previous
//
#include <hip/hip_runtime.h>
#include <cstdint>
#include <cstddef>

// 2-layer GCN. norm factorization: out[d] = dinv[d]*(h_s[d] + sum_{s->d} h_s[s]),
// h_s[i] = dinv[i]*(x@W)[i]. Self-loop folded in as the h_s[d] term.
// Edge aggregation: deterministic-layout 2-level counting sort -> CSR -> per-node
// scalar 8-wide gather. GEMM2 fused into the layer-1 gather epilogue.

#define SHIFT 8                 // 256 nodes per coarse bucket
#define NPB 256
#define CHUNK 8192              // edges per histogram/scatter block
#define IMG_CAP 6144            // LDS csr-image capacity (avg bucket load 4096, sigma~64)

// ---- K1: per-block bucket histogram. hist[b*nWG + w] = count of bucket b in block w ----
__global__ __launch_bounds__(256) void hist_kernel(const int* __restrict__ dst, int E, int nWG,
                                                   int B, int* __restrict__ hist) {
  __shared__ int h[256];
  int t = threadIdx.x, w = blockIdx.x;
  for (int i = t; i < B; i += 256) h[i] = 0;
  __syncthreads();
  int beg = w * CHUNK, end = min(beg + CHUNK, E);
  for (int i = beg + t; i < end; i += 256) atomicAdd(&h[dst[i] >> SHIFT], 1);
  __syncthreads();
  for (int i = t; i < B; i += 256) hist[i * nWG + w] = h[i];
}

// ---- K2: exclusive scan of each bucket row (over blocks); also row total ----
__global__ __launch_bounds__(256) void rowscan_kernel(const int* __restrict__ hist, int nWG,
                                                      int* __restrict__ rowscan, int* __restrict__ total) {
  int b = blockIdx.x, t = threadIdx.x;  // nWG <= 256
  int v = (t < nWG) ? hist[b * nWG + t] : 0;
  int lane = t & 63, wid = t >> 6;
  int x = v;
#pragma unroll
  for (int o = 1; o < 64; o <<= 1) { int y = __shfl_up(x, o, 64); if (lane >= o) x += y; }
  __shared__ int wsum[4];
  if (lane == 63) wsum[wid] = x;
  __syncthreads();
  int bw = 0;
  for (int i = 0; i < wid; ++i) bw += wsum[i];
  int incl = bw + x;
  if (t < nWG) rowscan[b * nWG + t] = incl - v;
  if (t == nWG - 1) total[b] = incl;
}

// ---- K3: LDS-staged scatter of packed keys (local<<16 | src) into bucket layout ----
// Each block recomputes base[] from total[] in-block (no extra kernel, no fences).
__global__ __launch_bounds__(256) void scatterkeys_kernel(const int* __restrict__ src,
                                                          const int* __restrict__ dst, int E, int nWG,
                                                          int B, const int* __restrict__ rowscan,
                                                          const int* __restrict__ total,
                                                          unsigned* __restrict__ keys) {
  __shared__ int h[256], loffs[256], cur[256], gb[256];
  __shared__ int wsum[4];
  __shared__ unsigned image[CHUNK];  // 32 KB
  __shared__ int gdst[CHUNK];        // 32 KB
  int t = threadIdx.x, w = blockIdx.x;
  int lane = t & 63, wid = t >> 6;
  // in-block exclusive scan of total[] -> gb[b] = base[b] + rowscan[b][w]
  {
    int v = (t < B) ? total[t] : 0;
    int x = v;
#pragma unroll
    for (int o = 1; o < 64; o <<= 1) { int y = __shfl_up(x, o, 64); if (lane >= o) x += y; }
    if (lane == 63) wsum[wid] = x;
    __syncthreads();
    int bw = 0;
    for (int i = 0; i < wid; ++i) bw += wsum[i];
    int excl = bw + x - v;
    if (t < B) gb[t] = excl + rowscan[t * nWG + w];
  }
  // local hist
  for (int i = t; i < B; i += 256) h[i] = 0;
  __syncthreads();
  int beg = w * CHUNK, end = min(beg + CHUNK, E);
  for (int i = beg + t; i < end; i += 256) atomicAdd(&h[dst[i] >> SHIFT], 1);
  __syncthreads();
  // local exclusive scan of h -> loffs/cur
  {
    int v = (t < B) ? h[t] : 0;
    int x = v;
#pragma unroll
    for (int o = 1; o < 64; o <<= 1) { int y = __shfl_up(x, o, 64); if (lane >= o) x += y; }
    if (lane == 63) wsum[wid] = x;
    __syncthreads();
    int bw = 0;
    for (int i = 0; i < wid; ++i) bw += wsum[i];
    int excl = bw + x - v;
    if (t < B) { loffs[t] = excl; cur[t] = excl; }
  }
  __syncthreads();
  // place into LDS image with precomputed global destination
  for (int i = beg + t; i < end; i += 256) {
    int d = dst[i], s = src[i];
    int b = d >> SHIFT;
    int p = atomicAdd(&cur[b], 1);
    image[p] = ((unsigned)(d & (NPB - 1)) << 16) | (unsigned)s;  // N <= 65536
    gdst[p] = gb[b] + (p - loffs[b]);
  }
  __syncthreads();
  // sequential write-out: consecutive lanes -> consecutive addresses within runs
  int n = end - beg;
  for (int i = t; i < n; i += 256) keys[gdst[i]] = image[i];
}

// ---- K4: per-bucket: per-node counts -> eoff/ecnt/dinv; sort keys -> csr (LDS image) ----
__global__ __launch_bounds__(256) void bucket_build_kernel(const unsigned* __restrict__ keys,
                                                           const int* __restrict__ total, int B, int N,
                                                           int* __restrict__ csr, int* __restrict__ eoff,
                                                           int* __restrict__ ecnt, float* __restrict__ dinv) {
  __shared__ int cnt[NPB], loffs[NPB], cur[NPB];
  __shared__ int red[4];
  __shared__ int image[IMG_CAP];
  int b = blockIdx.x, t = threadIdx.x;
  int lane = t & 63, wid = t >> 6;
  // gbeg = sum_{i<b} total[i] (in-block reduce)
  int part = 0;
  for (int i = t; i < b; i += 256) part += total[i];
#pragma unroll
  for (int o = 32; o > 0; o >>= 1) part += __shfl_down(part, o, 64);
  if (lane == 0) red[wid] = part;
  __syncthreads();
  int gbeg = red[0] + red[1] + red[2] + red[3];
  int m = total[b];
  int gend = gbeg + m;
  int nb = b << SHIFT;
  int nn = min(NPB, N - nb);
  cnt[t] = 0;  // NPB == blockDim
  __syncthreads();
  for (int i = gbeg + t; i < gend; i += 256) atomicAdd(&cnt[keys[i] >> 16], 1);
  __syncthreads();
  if (t < 64) {  // 4-per-lane exclusive scan of cnt[0..255] in one wave
    int v0 = cnt[4 * t], v1 = cnt[4 * t + 1], v2 = cnt[4 * t + 2], v3 = cnt[4 * t + 3];
    int s = v0 + v1 + v2 + v3, x = s;
#pragma unroll
    for (int o = 1; o < 64; o <<= 1) { int y = __shfl_up(x, o, 64); if (t >= o) x += y; }
    int e = x - s;
    loffs[4 * t] = e;                 cur[4 * t] = e;
    loffs[4 * t + 1] = e + v0;        cur[4 * t + 1] = e + v0;
    loffs[4 * t + 2] = e + v0 + v1;   cur[4 * t + 2] = e + v0 + v1;
    loffs[4 * t + 3] = e + v0 + v1 + v2; cur[4 * t + 3] = e + v0 + v1 + v2;
  }
  __syncthreads();
  for (int n2 = t; n2 < nn; n2 += 256) {
    eoff[nb + n2] = gbeg + loffs[n2];
    ecnt[nb + n2] = cnt[n2];
    dinv[nb + n2] = 1.0f / sqrtf((float)(cnt[n2] + 1));  // +1 self-loop
  }
  if (m <= IMG_CAP) {
    for (int i = gbeg + t; i < gend; i += 256) {
      unsigned k = keys[i];
      int p = atomicAdd(&cur[k >> 16], 1);
      image[p] = (int)(k & 0xFFFFu);
    }
    __syncthreads();
    for (int i = t; i < m; i += 256) csr[gbeg + i] = image[i];
  } else {  // statistically unreachable fallback
    for (int i = gbeg + t; i < gend; i += 256) {
      unsigned k = keys[i];
      int p = atomicAdd(&cur[k >> 16], 1);
      csr[gbeg + p] = (int)(k & 0xFFFFu);
    }
  }
}

// ---- GEMM1: h1s[i][c] = dinv[i] * (x @ W1)[i][c]   (N x 128 @ 128 x 64) ----
__global__ __launch_bounds__(256) void gemm1_kernel(
    const float* __restrict__ x, const float* __restrict__ W1,
    const float* __restrict__ dinv, float* __restrict__ h1s, int N) {
  __shared__ float ws[128 * 64];
  __shared__ float xs[64 * 128];
  const int t = threadIdx.x;
  const int rowBase = blockIdx.x * 64;
  float4* ws4 = (float4*)ws;
  float4* xs4 = (float4*)xs;
  for (int i = t; i < 128 * 16; i += 256) ws4[i] = ((const float4*)W1)[i];
  for (int i = t; i < 64 * 32; i += 256) {
    int r = i >> 5, kq = i & 31;
    int row = rowBase + r;
    float4 v = make_float4(0.f, 0.f, 0.f, 0.f);
    if (row < N) v = ((const float4*)x)[(size_t)row * 32 + kq];
    xs4[r * 32 + (kq ^ ((r >> 2) & 7))] = v;
  }
  __syncthreads();
  const int g = t & 15;
  const int rg = t >> 4;
  const int swz = rg & 7;
  float acc[4][4] = {};
  for (int kq = 0; kq < 32; ++kq) {
    float4 a[4];
#pragma unroll
    for (int j = 0; j < 4; ++j) a[j] = xs4[(4 * rg + j) * 32 + (kq ^ swz)];
    float4 w[4];
#pragma unroll
    for (int kk = 0; kk < 4; ++kk) w[kk] = ws4[(4 * kq + kk) * 16 + g];
#pragma unroll
    for (int j = 0; j < 4; ++j) {
      acc[j][0] += a[j].x * w[0].x + a[j].y * w[1].x + a[j].z * w[2].x + a[j].w * w[3].x;
      acc[j][1] += a[j].x * w[0].y + a[j].y * w[1].y + a[j].z * w[2].y + a[j].w * w[3].y;
      acc[j][2] += a[j].x * w[0].z + a[j].y * w[1].z + a[j].z * w[2].z + a[j].w * w[3].z;
      acc[j][3] += a[j].x * w[0].w + a[j].y * w[1].w + a[j].z * w[2].w + a[j].w * w[3].w;
    }
  }
#pragma unroll
  for (int j = 0; j < 4; ++j) {
    int row = rowBase + 4 * rg + j;
    if (row < N) {
      float dv = dinv[row];
      float4 o = make_float4(acc[j][0] * dv, acc[j][1] * dv, acc[j][2] * dv, acc[j][3] * dv);
      ((float4*)h1s)[(size_t)row * 16 + g] = o;
    }
  }
}

// ---- gather layer 1 + fused GEMM2 ----
// 1 wave/node, lane = feature, scalar 8-wide ILP gather; epilogue computes
// h2s[d][c] = dinv[d] * (relu(acc*dinv[d]+b1) @ W2)[c] via LDS (W2 + per-wave a1 row).
__global__ __launch_bounds__(256) void gather64_gemm2_kernel(
    const float* __restrict__ h1s, const int* __restrict__ csr, const int* __restrict__ eoff,
    const int* __restrict__ ecnt, const float* __restrict__ dinv, const float* __restrict__ b1,
    const float* __restrict__ W2, float* __restrict__ h2s, int N) {
  __shared__ float w2s[64 * 32];  // 8 KB, [k][c]
  __shared__ float arow[4 * 64];  // per-wave a1 row
  int t = threadIdx.x;
  float4* w2s4 = (float4*)w2s;
  for (int i = t; i < 512; i += 256) w2s4[i] = ((const float4*)W2)[i];
  __syncthreads();  // all threads participate before any divergent exit
  int d = blockIdx.x * 4 + (t >> 6);
  if (d >= N) return;
  int lane = t & 63;
  int wid = t >> 6;
  int beg = eoff[d], m = ecnt[d];
  float a0 = h1s[(size_t)d * 64 + lane], aA = 0.f, aB = 0.f, aC = 0.f;  // self-loop
  int j = 0;
  for (; j + 8 <= m; j += 8) {
    int s0 = csr[beg + j + 0], s1 = csr[beg + j + 1], s2 = csr[beg + j + 2], s3 = csr[beg + j + 3];
    int s4 = csr[beg + j + 4], s5 = csr[beg + j + 5], s6 = csr[beg + j + 6], s7 = csr[beg + j + 7];
    float v0 = h1s[(size_t)s0 * 64 + lane], v1 = h1s[(size_t)s1 * 64 + lane];
    float v2 = h1s[(size_t)s2 * 64 + lane], v3 = h1s[(size_t)s3 * 64 + lane];
    float v4 = h1s[(size_t)s4 * 64 + lane], v5 = h1s[(size_t)s5 * 64 + lane];
    float v6 = h1s[(size_t)s6 * 64 + lane], v7 = h1s[(size_t)s7 * 64 + lane];
    a0 += v0; aA += v1; aB += v2; aC += v3;
    a0 += v4; aA += v5; aB += v6; aC += v7;
  }
  for (; j + 4 <= m; j += 4) {
    int s0 = csr[beg + j + 0], s1 = csr[beg + j + 1], s2 = csr[beg + j + 2], s3 = csr[beg + j + 3];
    float v0 = h1s[(size_t)s0 * 64 + lane], v1 = h1s[(size_t)s1 * 64 + lane];
    float v2 = h1s[(size_t)s2 * 64 + lane], v3 = h1s[(size_t)s3 * 64 + lane];
    a0 += v0; aA += v1; aB += v2; aC += v3;
  }
  for (; j < m; ++j) a0 += h1s[(size_t)csr[beg + j] * 64 + lane];
  float acc = (a0 + aA) + (aB + aC);
  float dv = dinv[d];
  float a1v = fmaxf(acc * dv + b1[lane], 0.f);
  arow[wid * 64 + lane] = a1v;  // same-wave LDS RAW: hw waitcnt, no barrier needed
  // fused GEMM2: c = lane&31, halves split K, combine via shfl_xor(32)
  int c = lane & 31, half = lane >> 5;
  const float* ar = &arow[wid * 64 + half * 32];
  const float* wp = &w2s[half * 32 * 32 + c];
  float s = 0.f;
#pragma unroll
  for (int kk = 0; kk < 32; ++kk) s += ar[kk] * wp[kk * 32];  // 2-way bank alias = free
  s += __shfl_xor(s, 32, 64);
  if (half == 0) h2s[(size_t)d * 32 + c] = s * dv;
}

// ---- gather layer 2: 2 nodes/wave, 32-lane rows, scalar 8-wide ILP ----
__global__ __launch_bounds__(256) void gather32_kernel(
    const float* __restrict__ h2s, const int* __restrict__ csr, const int* __restrict__ eoff,
    const int* __restrict__ ecnt, const float* __restrict__ dinv, const float* __restrict__ b2,
    float* __restrict__ out, int N) {
  int t = threadIdx.x;
  int d = blockIdx.x * 8 + (t >> 5);
  if (d >= N) return;
  int f = t & 31;
  int beg = eoff[d], m = ecnt[d];
  float a0 = h2s[(size_t)d * 32 + f], aA = 0.f, aB = 0.f, aC = 0.f;  // self-loop
  int j = 0;
  for (; j + 8 <= m; j += 8) {
    int s0 = csr[beg + j + 0], s1 = csr[beg + j + 1], s2 = csr[beg + j + 2], s3 = csr[beg + j + 3];
    int s4 = csr[beg + j + 4], s5 = csr[beg + j + 5], s6 = csr[beg + j + 6], s7 = csr[beg + j + 7];
    float v0 = h2s[(size_t)s0 * 32 + f], v1 = h2s[(size_t)s1 * 32 + f];
    float v2 = h2s[(size_t)s2 * 32 + f], v3 = h2s[(size_t)s3 * 32 + f];
    float v4 = h2s[(size_t)s4 * 32 + f], v5 = h2s[(size_t)s5 * 32 + f];
    float v6 = h2s[(size_t)s6 * 32 + f], v7 = h2s[(size_t)s7 * 32 + f];
    a0 += v0; aA += v1; aB += v2; aC += v3;
    a0 += v4; aA += v5; aB += v6; aC += v7;
  }
  for (; j + 4 <= m; j += 4) {
    int s0 = csr[beg + j + 0], s1 = csr[beg + j + 1], s2 = csr[beg + j + 2], s3 = csr[beg + j + 3];
    float v0 = h2s[(size_t)s0 * 32 + f], v1 = h2s[(size_t)s1 * 32 + f];
    float v2 = h2s[(size_t)s2 * 32 + f], v3 = h2s[(size_t)s3 * 32 + f];
    a0 += v0; aA += v1; aB += v2; aC += v3;
  }
  for (; j < m; ++j) a0 += h2s[(size_t)csr[beg + j] * 32 + f];
  out[(size_t)d * 32 + f] = ((a0 + aA) + (aB + aC)) * dinv[d] + b2[f];
}

extern "C" void kernel_launch(void* const* d_in, const int* in_sizes, int n_in,
                              void* d_out, int out_size, void* d_ws, size_t ws_size,
                              hipStream_t stream) {
  const float* x = (const float*)d_in[0];
  const int* edge_index = (const int*)d_in[1];
  // d_in[2] = edge_attr (unused by reference)
  const float* W1 = (const float*)d_in[3];
  const float* b1 = (const float*)d_in[4];
  const float* W2 = (const float*)d_in[5];
  const float* b2 = (const float*)d_in[6];
  float* out = (float*)d_out;

  const int N = in_sizes[0] / 128;  // 50000 (key packing requires <= 65536)
  const int E = in_sizes[1] / 2;    // 800000
  const int* src = edge_index;
  const int* dst = edge_index + E;

  const int B = (N + NPB - 1) >> SHIFT;     // 196 buckets
  const int nWG = (E + CHUNK - 1) / CHUNK;  // 98 blocks

  char* ws = (char*)d_ws;
  size_t off = 0;
  auto alloc = [&](size_t bytes) -> void* {
    void* p = ws + off;
    off += (bytes + 255) & ~(size_t)255;
    return p;
  };
  unsigned* keys = (unsigned*)alloc((size_t)E * 4);
  int* csr = (int*)alloc((size_t)E * 4);
  int* hist = (int*)alloc((size_t)B * nWG * 4);
  int* rowscan = (int*)alloc((size_t)B * nWG * 4);
  int* total = (int*)alloc((size_t)B * 4);
  int* eoff = (int*)alloc((size_t)N * 4);
  int* ecnt = (int*)alloc((size_t)N * 4);
  float* dinv = (float*)alloc((size_t)N * 4);
  float* h1s = (float*)alloc((size_t)N * 64 * 4);
  float* h2s = (float*)alloc((size_t)N * 32 * 4);

  hist_kernel<<<nWG, 256, 0, stream>>>(dst, E, nWG, B, hist);
  rowscan_kernel<<<B, 256, 0, stream>>>(hist, nWG, rowscan, total);
  scatterkeys_kernel<<<nWG, 256, 0, stream>>>(src, dst, E, nWG, B, rowscan, total, keys);
  bucket_build_kernel<<<B, 256, 0, stream>>>(keys, total, B, N, csr, eoff, ecnt, dinv);
  gemm1_kernel<<<(N + 63) / 64, 256, 0, stream>>>(x, W1, dinv, h1s, N);
  gather64_gemm2_kernel<<<(N + 3) / 4, 256, 0, stream>>>(h1s, csr, eoff, ecnt, dinv, b1, W2, h2s, N);
  gather32_kernel<<<(N + 7) / 8, 256, 0, stream>>>(h2s, csr, eoff, ecnt, dinv, b2, out, N);
}

// Round 6
// 107.202 us; speedup vs baseline: 1.2448x; 1.1331x over previous
//
#include <hip/hip_runtime.h>
#include <hip/hip_fp16.h>
#include <cstdint>
#include <cstddef>

// 2-layer GCN. norm factorization: out[d] = dinv[d]*(h_s[d] + sum_{s->d} h_s[s]),
// h_s[i] = dinv[i]*(x@W)[i]. Self-loop folded in as the h_s[d] term.
// Edge aggregation: deterministic-layout 2-level counting sort -> CSR -> per-node
// gather. Hidden layers stored fp16 (halves gather line traffic); all accumulation f32.
// GEMM2 fused into the layer-1 gather epilogue.

#define SHIFT 8                 // 256 nodes per coarse bucket
#define NPB 256
#define CHUNK 8192              // edges per histogram/scatter block
#define IMG_CAP 6144            // LDS csr-image capacity (avg bucket load ~4081, sigma~64)

// ---- K1: per-block bucket histogram. hist[b*nWG + w] = count of bucket b in block w ----
__global__ __launch_bounds__(256) void hist_kernel(const int* __restrict__ dst, int E, int nWG,
                                                   int B, int* __restrict__ hist) {
  __shared__ int h[256];
  int t = threadIdx.x, w = blockIdx.x;
  for (int i = t; i < B; i += 256) h[i] = 0;
  __syncthreads();
  int beg = w * CHUNK, end = min(beg + CHUNK, E);
  for (int i = beg + t; i < end; i += 256) atomicAdd(&h[dst[i] >> SHIFT], 1);
  __syncthreads();
  for (int i = t; i < B; i += 256) hist[i * nWG + w] = h[i];
}

// ---- K2: exclusive scan of each bucket row (over blocks); also row total ----
__global__ __launch_bounds__(256) void rowscan_kernel(const int* __restrict__ hist, int nWG,
                                                      int* __restrict__ rowscan, int* __restrict__ total) {
  int b = blockIdx.x, t = threadIdx.x;  // nWG <= 256
  int v = (t < nWG) ? hist[b * nWG + t] : 0;
  int lane = t & 63, wid = t >> 6;
  int x = v;
#pragma unroll
  for (int o = 1; o < 64; o <<= 1) { int y = __shfl_up(x, o, 64); if (lane >= o) x += y; }
  __shared__ int wsum[4];
  if (lane == 63) wsum[wid] = x;
  __syncthreads();
  int bw = 0;
  for (int i = 0; i < wid; ++i) bw += wsum[i];
  int incl = bw + x;
  if (t < nWG) rowscan[b * nWG + t] = incl - v;
  if (t == nWG - 1) total[b] = incl;
}

// ---- K3: LDS-staged scatter of packed keys (local<<16 | src) into bucket layout ----
// Reuses hist[] for the local per-bucket counts (no second histogram pass).
__global__ __launch_bounds__(256) void scatterkeys_kernel(const int* __restrict__ src,
                                                          const int* __restrict__ dst, int E, int nWG,
                                                          int B, const int* __restrict__ hist,
                                                          const int* __restrict__ rowscan,
                                                          const int* __restrict__ total,
                                                          unsigned* __restrict__ keys) {
  __shared__ int loffs[256], cur[256], gb[256];
  __shared__ int wsum[4];
  __shared__ unsigned image[CHUNK];  // 32 KB
  __shared__ int gdst[CHUNK];        // 32 KB
  int t = threadIdx.x, w = blockIdx.x;
  int lane = t & 63, wid = t >> 6;
  // in-block exclusive scan of total[] -> gb[b] = base[b] + rowscan[b][w]
  {
    int v = (t < B) ? total[t] : 0;
    int x = v;
#pragma unroll
    for (int o = 1; o < 64; o <<= 1) { int y = __shfl_up(x, o, 64); if (lane >= o) x += y; }
    if (lane == 63) wsum[wid] = x;
    __syncthreads();
    int bw = 0;
    for (int i = 0; i < wid; ++i) bw += wsum[i];
    int excl = bw + x - v;
    if (t < B) gb[t] = excl + rowscan[t * nWG + w];
  }
  __syncthreads();
  // local exclusive scan of this block's hist row -> loffs/cur
  {
    int v = (t < B) ? hist[t * nWG + w] : 0;
    int x = v;
#pragma unroll
    for (int o = 1; o < 64; o <<= 1) { int y = __shfl_up(x, o, 64); if (lane >= o) x += y; }
    if (lane == 63) wsum[wid] = x;
    __syncthreads();
    int bw = 0;
    for (int i = 0; i < wid; ++i) bw += wsum[i];
    int excl = bw + x - v;
    if (t < B) { loffs[t] = excl; cur[t] = excl; }
  }
  __syncthreads();
  // place into LDS image with precomputed global destination
  int beg = w * CHUNK, end = min(beg + CHUNK, E);
  for (int i = beg + t; i < end; i += 256) {
    int d = dst[i], s = src[i];
    int b = d >> SHIFT;
    int p = atomicAdd(&cur[b], 1);
    image[p] = ((unsigned)(d & (NPB - 1)) << 16) | (unsigned)s;  // N <= 65536
    gdst[p] = gb[b] + (p - loffs[b]);
  }
  __syncthreads();
  // sequential write-out: consecutive lanes -> consecutive addresses within runs
  int n = end - beg;
  for (int i = t; i < n; i += 256) keys[gdst[i]] = image[i];
}

// ---- K4: per-bucket: per-node counts -> eoff/ecnt/dinv; sort keys -> csr (LDS image) ----
__global__ __launch_bounds__(256) void bucket_build_kernel(const unsigned* __restrict__ keys,
                                                           const int* __restrict__ total, int B, int N,
                                                           int* __restrict__ csr, int* __restrict__ eoff,
                                                           int* __restrict__ ecnt, float* __restrict__ dinv) {
  __shared__ int cnt[NPB], loffs[NPB], cur[NPB];
  __shared__ int red[4];
  __shared__ int image[IMG_CAP];
  int b = blockIdx.x, t = threadIdx.x;
  int lane = t & 63, wid = t >> 6;
  // gbeg = sum_{i<b} total[i] (in-block reduce)
  int part = 0;
  for (int i = t; i < b; i += 256) part += total[i];
#pragma unroll
  for (int o = 32; o > 0; o >>= 1) part += __shfl_down(part, o, 64);
  if (lane == 0) red[wid] = part;
  __syncthreads();
  int gbeg = red[0] + red[1] + red[2] + red[3];
  int m = total[b];
  int gend = gbeg + m;
  int nb = b << SHIFT;
  int nn = min(NPB, N - nb);
  cnt[t] = 0;  // NPB == blockDim
  __syncthreads();
  for (int i = gbeg + t; i < gend; i += 256) atomicAdd(&cnt[keys[i] >> 16], 1);
  __syncthreads();
  if (t < 64) {  // 4-per-lane exclusive scan of cnt[0..255] in one wave
    int v0 = cnt[4 * t], v1 = cnt[4 * t + 1], v2 = cnt[4 * t + 2], v3 = cnt[4 * t + 3];
    int s = v0 + v1 + v2 + v3, x = s;
#pragma unroll
    for (int o = 1; o < 64; o <<= 1) { int y = __shfl_up(x, o, 64); if (t >= o) x += y; }
    int e = x - s;
    loffs[4 * t] = e;                 cur[4 * t] = e;
    loffs[4 * t + 1] = e + v0;        cur[4 * t + 1] = e + v0;
    loffs[4 * t + 2] = e + v0 + v1;   cur[4 * t + 2] = e + v0 + v1;
    loffs[4 * t + 3] = e + v0 + v1 + v2; cur[4 * t + 3] = e + v0 + v1 + v2;
  }
  __syncthreads();
  for (int n2 = t; n2 < nn; n2 += 256) {
    eoff[nb + n2] = gbeg + loffs[n2];
    ecnt[nb + n2] = cnt[n2];
    dinv[nb + n2] = 1.0f / sqrtf((float)(cnt[n2] + 1));  // +1 self-loop
  }
  if (m <= IMG_CAP) {
    for (int i = gbeg + t; i < gend; i += 256) {
      unsigned k = keys[i];
      int p = atomicAdd(&cur[k >> 16], 1);
      image[p] = (int)(k & 0xFFFFu);
    }
    __syncthreads();
    for (int i = t; i < m; i += 256) csr[gbeg + i] = image[i];
  } else {  // statistically unreachable fallback
    for (int i = gbeg + t; i < gend; i += 256) {
      unsigned k = keys[i];
      int p = atomicAdd(&cur[k >> 16], 1);
      csr[gbeg + p] = (int)(k & 0xFFFFu);
    }
  }
}

// ---- GEMM1: h1s[i][c] = fp16( dinv[i] * (x @ W1)[i][c] )   (N x 128 @ 128 x 64) ----
__global__ __launch_bounds__(256) void gemm1_kernel(
    const float* __restrict__ x, const float* __restrict__ W1,
    const float* __restrict__ dinv, __half* __restrict__ h1s, int N) {
  __shared__ float ws[128 * 64];
  __shared__ float xs[64 * 128];
  const int t = threadIdx.x;
  const int rowBase = blockIdx.x * 64;
  float4* ws4 = (float4*)ws;
  float4* xs4 = (float4*)xs;
  for (int i = t; i < 128 * 16; i += 256) ws4[i] = ((const float4*)W1)[i];
  for (int i = t; i < 64 * 32; i += 256) {
    int r = i >> 5, kq = i & 31;
    int row = rowBase + r;
    float4 v = make_float4(0.f, 0.f, 0.f, 0.f);
    if (row < N) v = ((const float4*)x)[(size_t)row * 32 + kq];
    xs4[r * 32 + (kq ^ ((r >> 2) & 7))] = v;
  }
  __syncthreads();
  const int g = t & 15;
  const int rg = t >> 4;
  const int swz = rg & 7;
  float acc[4][4] = {};
  for (int kq = 0; kq < 32; ++kq) {
    float4 a[4];
#pragma unroll
    for (int j = 0; j < 4; ++j) a[j] = xs4[(4 * rg + j) * 32 + (kq ^ swz)];
    float4 w[4];
#pragma unroll
    for (int kk = 0; kk < 4; ++kk) w[kk] = ws4[(4 * kq + kk) * 16 + g];
#pragma unroll
    for (int j = 0; j < 4; ++j) {
      acc[j][0] += a[j].x * w[0].x + a[j].y * w[1].x + a[j].z * w[2].x + a[j].w * w[3].x;
      acc[j][1] += a[j].x * w[0].y + a[j].y * w[1].y + a[j].z * w[2].y + a[j].w * w[3].y;
      acc[j][2] += a[j].x * w[0].z + a[j].y * w[1].z + a[j].z * w[2].z + a[j].w * w[3].z;
      acc[j][3] += a[j].x * w[0].w + a[j].y * w[1].w + a[j].z * w[2].w + a[j].w * w[3].w;
    }
  }
#pragma unroll
  for (int j = 0; j < 4; ++j) {
    int row = rowBase + 4 * rg + j;
    if (row < N) {
      float dv = dinv[row];
      union { __half2 h2[2]; float2 f2v; } u;
      u.h2[0] = __floats2half2_rn(acc[j][0] * dv, acc[j][1] * dv);
      u.h2[1] = __floats2half2_rn(acc[j][2] * dv, acc[j][3] * dv);
      ((float2*)h1s)[(size_t)row * 16 + g] = u.f2v;
    }
  }
}

// ---- gather layer 1 + fused GEMM2 ----
// 2 nodes/wave (32 lanes x half2 = 64 feats), 16-deep ILP gather, f32 accumulate.
// Epilogue: a1 row -> LDS; h2s[d][c] = fp16( dinv[d] * (relu(acc*dinv+b1) @ W2)[c] ).
__global__ __launch_bounds__(256) void gather64_gemm2_kernel(
    const __half* __restrict__ h1s, const int* __restrict__ csr, const int* __restrict__ eoff,
    const int* __restrict__ ecnt, const float* __restrict__ dinv, const float* __restrict__ b1,
    const float* __restrict__ W2, __half* __restrict__ h2s, int N) {
  __shared__ float w2s[64 * 32];  // 8 KB, [k][c]
  __shared__ float arow[8 * 64];  // per-half-wave a1 row (8 nodes/block)
  int t = threadIdx.x;
  float4* w2s4 = (float4*)w2s;
  for (int i = t; i < 512; i += 256) w2s4[i] = ((const float4*)W2)[i];
  __syncthreads();  // all threads participate before any divergent exit
  int slot = t >> 5;                 // 0..7 node slot in block
  int d = blockIdx.x * 8 + slot;
  if (d >= N) return;
  int f2 = t & 31;                   // half2 column (feats 2f2, 2f2+1)
  const __half2* h1p = (const __half2*)h1s;  // row stride 32 half2
  int beg = eoff[d], m = ecnt[d];
  float2 a0 = __half22float2(h1p[(size_t)d * 32 + f2]);  // self-loop
  float2 aA = make_float2(0.f, 0.f), aB = make_float2(0.f, 0.f), aC = make_float2(0.f, 0.f);
  int j = 0;
  for (; j + 16 <= m; j += 16) {
    int s[16];
#pragma unroll
    for (int i = 0; i < 16; ++i) s[i] = csr[beg + j + i];
    __half2 v[16];
#pragma unroll
    for (int i = 0; i < 16; ++i) v[i] = h1p[(size_t)s[i] * 32 + f2];
#pragma unroll
    for (int i = 0; i < 16; ++i) {
      float2 f = __half22float2(v[i]);
      float2* ac = (i & 3) == 0 ? &a0 : (i & 3) == 1 ? &aA : (i & 3) == 2 ? &aB : &aC;
      ac->x += f.x; ac->y += f.y;
    }
  }
  for (; j + 4 <= m; j += 4) {
    int s0 = csr[beg + j], s1 = csr[beg + j + 1], s2 = csr[beg + j + 2], s3 = csr[beg + j + 3];
    __half2 v0 = h1p[(size_t)s0 * 32 + f2], v1 = h1p[(size_t)s1 * 32 + f2];
    __half2 v2 = h1p[(size_t)s2 * 32 + f2], v3 = h1p[(size_t)s3 * 32 + f2];
    float2 f0 = __half22float2(v0), f1 = __half22float2(v1);
    float2 f2v = __half22float2(v2), f3 = __half22float2(v3);
    a0.x += f0.x; a0.y += f0.y; aA.x += f1.x; aA.y += f1.y;
    aB.x += f2v.x; aB.y += f2v.y; aC.x += f3.x; aC.y += f3.y;
  }
  for (; j < m; ++j) {
    float2 f = __half22float2(h1p[(size_t)csr[beg + j] * 32 + f2]);
    a0.x += f.x; a0.y += f.y;
  }
  float sx = (a0.x + aA.x) + (aB.x + aC.x);
  float sy = (a0.y + aA.y) + (aB.y + aC.y);
  float dv = dinv[d];
  float2 bb = ((const float2*)b1)[f2];
  float ax = fmaxf(sx * dv + bb.x, 0.f);
  float ay = fmaxf(sy * dv + bb.y, 0.f);
  ((float2*)arow)[slot * 32 + f2] = make_float2(ax, ay);  // same-wave LDS RAW
  // fused GEMM2: lane computes output col c = f2 for its node
  const float* ar = &arow[slot * 64];
  float s = 0.f;
#pragma unroll
  for (int kk = 0; kk < 64; ++kk) s += ar[kk] * w2s[kk * 32 + f2];  // broadcast + 2-way alias
  h2s[(size_t)d * 32 + f2] = __float2half_rn(s * dv);
}

// ---- gather layer 2: 4 nodes/wave (16 lanes x half2 = 32 feats), 16-deep ILP ----
__global__ __launch_bounds__(256) void gather32_kernel(
    const __half* __restrict__ h2s, const int* __restrict__ csr, const int* __restrict__ eoff,
    const int* __restrict__ ecnt, const float* __restrict__ dinv, const float* __restrict__ b2,
    float* __restrict__ out, int N) {
  int t = threadIdx.x;
  int d = blockIdx.x * 16 + (t >> 4);
  if (d >= N) return;
  int f2 = t & 15;  // half2 column (feats 2f2, 2f2+1)
  const __half2* h2p = (const __half2*)h2s;  // row stride 16 half2
  int beg = eoff[d], m = ecnt[d];
  float2 a0 = __half22float2(h2p[(size_t)d * 16 + f2]);  // self-loop
  float2 aA = make_float2(0.f, 0.f), aB = make_float2(0.f, 0.f), aC = make_float2(0.f, 0.f);
  int j = 0;
  for (; j + 16 <= m; j += 16) {
    int s[16];
#pragma unroll
    for (int i = 0; i < 16; ++i) s[i] = csr[beg + j + i];
    __half2 v[16];
#pragma unroll
    for (int i = 0; i < 16; ++i) v[i] = h2p[(size_t)s[i] * 16 + f2];
#pragma unroll
    for (int i = 0; i < 16; ++i) {
      float2 f = __half22float2(v[i]);
      float2* ac = (i & 3) == 0 ? &a0 : (i & 3) == 1 ? &aA : (i & 3) == 2 ? &aB : &aC;
      ac->x += f.x; ac->y += f.y;
    }
  }
  for (; j + 4 <= m; j += 4) {
    int s0 = csr[beg + j], s1 = csr[beg + j + 1], s2 = csr[beg + j + 2], s3 = csr[beg + j + 3];
    __half2 v0 = h2p[(size_t)s0 * 16 + f2], v1 = h2p[(size_t)s1 * 16 + f2];
    __half2 v2 = h2p[(size_t)s2 * 16 + f2], v3 = h2p[(size_t)s3 * 16 + f2];
    float2 f0 = __half22float2(v0), f1 = __half22float2(v1);
    float2 f2v = __half22float2(v2), f3 = __half22float2(v3);
    a0.x += f0.x; a0.y += f0.y; aA.x += f1.x; aA.y += f1.y;
    aB.x += f2v.x; aB.y += f2v.y; aC.x += f3.x; aC.y += f3.y;
  }
  for (; j < m; ++j) {
    float2 f = __half22float2(h2p[(size_t)csr[beg + j] * 16 + f2]);
    a0.x += f.x; a0.y += f.y;
  }
  float sx = (a0.x + aA.x) + (aB.x + aC.x);
  float sy = (a0.y + aA.y) + (aB.y + aC.y);
  float dv = dinv[d];
  float2 bb = ((const float2*)b2)[f2];
  ((float2*)out)[(size_t)d * 16 + f2] = make_float2(sx * dv + bb.x, sy * dv + bb.y);
}

extern "C" void kernel_launch(void* const* d_in, const int* in_sizes, int n_in,
                              void* d_out, int out_size, void* d_ws, size_t ws_size,
                              hipStream_t stream) {
  const float* x = (const float*)d_in[0];
  const int* edge_index = (const int*)d_in[1];
  // d_in[2] = edge_attr (unused by reference)
  const float* W1 = (const float*)d_in[3];
  const float* b1 = (const float*)d_in[4];
  const float* W2 = (const float*)d_in[5];
  const float* b2 = (const float*)d_in[6];
  float* out = (float*)d_out;

  const int N = in_sizes[0] / 128;  // 50000 (key packing requires <= 65536)
  const int E = in_sizes[1] / 2;    // 800000
  const int* src = edge_index;
  const int* dst = edge_index + E;

  const int B = (N + NPB - 1) >> SHIFT;     // 196 buckets
  const int nWG = (E + CHUNK - 1) / CHUNK;  // 98 blocks

  char* ws = (char*)d_ws;
  size_t off = 0;
  auto alloc = [&](size_t bytes) -> void* {
    void* p = ws + off;
    off += (bytes + 255) & ~(size_t)255;
    return p;
  };
  unsigned* keys = (unsigned*)alloc((size_t)E * 4);
  int* csr = (int*)alloc((size_t)E * 4);
  int* hist = (int*)alloc((size_t)B * nWG * 4);
  int* rowscan = (int*)alloc((size_t)B * nWG * 4);
  int* total = (int*)alloc((size_t)B * 4);
  int* eoff = (int*)alloc((size_t)N * 4);
  int* ecnt = (int*)alloc((size_t)N * 4);
  float* dinv = (float*)alloc((size_t)N * 4);
  __half* h1s = (__half*)alloc((size_t)N * 64 * 2);
  __half* h2s = (__half*)alloc((size_t)N * 32 * 2);

  hist_kernel<<<nWG, 256, 0, stream>>>(dst, E, nWG, B, hist);
  rowscan_kernel<<<B, 256, 0, stream>>>(hist, nWG, rowscan, total);
  scatterkeys_kernel<<<nWG, 256, 0, stream>>>(src, dst, E, nWG, B, hist, rowscan, total, keys);
  bucket_build_kernel<<<B, 256, 0, stream>>>(keys, total, B, N, csr, eoff, ecnt, dinv);
  gemm1_kernel<<<(N + 63) / 64, 256, 0, stream>>>(x, W1, dinv, h1s, N);
  gather64_gemm2_kernel<<<(N + 7) / 8, 256, 0, stream>>>(h1s, csr, eoff, ecnt, dinv, b1, W2, h2s, N);
  gather32_kernel<<<(N + 15) / 16, 256, 0, stream>>>(h2s, csr, eoff, ecnt, dinv, b2, out, N);
}